// Round 1
// baseline (2043.340 us; speedup 1.0000x reference)
//
#include <hip/hip_runtime.h>

#define NN 100000

// ---------------- degree / norm ----------------
__global__ __launch_bounds__(256) void degree_kernel(const int* __restrict__ src,
                                                     const int* __restrict__ dst,
                                                     float* deg_out, float* deg_in, int E) {
    int e = blockIdx.x * blockDim.x + threadIdx.x;
    if (e < E) {
        atomicAdd(&deg_out[src[e]], 1.0f);
        atomicAdd(&deg_in[dst[e]], 1.0f);
    }
}

__global__ __launch_bounds__(256) void norm_kernel(float* deg_out, float* deg_in, int N) {
    int i = blockIdx.x * blockDim.x + threadIdx.x;
    if (i < N) {
        deg_out[i] = rsqrtf(fmaxf(deg_out[i], 1.0f));
        deg_in[i]  = rsqrtf(fmaxf(deg_in[i], 1.0f));
    }
}

// ---------------- edge scatter: agg[dst] += h[src] * norm_out[src] ----------------
template <int D>
__global__ __launch_bounds__(256) void scatter_kernel(const float* __restrict__ h,
                                                      const int* __restrict__ src,
                                                      const int* __restrict__ dst,
                                                      const float* __restrict__ norm_out,
                                                      float* agg, int E) {
    int idx = blockIdx.x * blockDim.x + threadIdx.x;
    int total = E * D;
    if (idx >= total) return;
    int e = idx / D;
    int f = idx - e * D;
    int s = src[e];
    int t = dst[e];
    float v = h[(long long)s * D + f] * norm_out[s];
    atomicAdd(&agg[(long long)t * D + f], v);
}

// ---------------- fused GEMM: out = [relu(] (A * norm_in) @ W [+ b ][)] ----------------
// EPILOGUE=true : scale A rows by norm_in while staging; add bias + relu on store.
// EPILOGUE=false: plain A @ W (used for layer-3 pre-propagation GEMM).
template <int K, int NOUT, bool EPILOGUE>
__global__ __launch_bounds__(256) void gemm_kernel(const float* __restrict__ A,
                                                   const float* __restrict__ W,
                                                   const float* __restrict__ b,
                                                   const float* __restrict__ norm_in,
                                                   float* __restrict__ out, int N) {
    constexpr int BM = 32;           // nodes per block
    constexpr int BK = 64;           // K chunk
    constexpr int NJ = (NOUT + 7) / 8;  // accumulators per thread

    __shared__ float Wl[BK * NOUT + 8];       // +8 pad: harmless OOB col reads for NOUT=47
    __shared__ float Al[BM * (BK + 1)];       // +1 pad breaks bank conflicts

    const int tid = threadIdx.x;
    const int nl = tid >> 3;   // 0..31 node-in-block
    const int tj = tid & 7;    // 0..7 column group
    const int block0 = blockIdx.x * BM;
    const int node = block0 + nl;

    float acc[NJ];
#pragma unroll
    for (int j = 0; j < NJ; ++j) acc[j] = 0.0f;

    for (int k0 = 0; k0 < K; k0 += BK) {
        // stage W chunk [BK x NOUT]
        for (int i = tid; i < BK * NOUT; i += 256) {
            int kk = i / NOUT;
            int c = i - kk * NOUT;
            int k = k0 + kk;
            Wl[i] = (k < K) ? W[k * NOUT + c] : 0.0f;
        }
        // stage A chunk [BM x BK], scaled by norm_in if EPILOGUE
        for (int i = tid; i < BM * BK; i += 256) {
            int r = i >> 6;          // BK==64
            int kk = i & 63;
            int nr = block0 + r;
            int k = k0 + kk;
            float v = 0.0f;
            if (nr < N && k < K) {
                v = A[(long long)nr * K + k];
                if (EPILOGUE) v *= norm_in[nr];
            }
            Al[r * (BK + 1) + kk] = v;
        }
        __syncthreads();

        for (int kk = 0; kk < BK; ++kk) {
            float a = Al[nl * (BK + 1) + kk];
#pragma unroll
            for (int j = 0; j < NJ; ++j)
                acc[j] += a * Wl[kk * NOUT + tj + 8 * j];
        }
        __syncthreads();
    }

    if (node < N) {
#pragma unroll
        for (int j = 0; j < NJ; ++j) {
            int c = tj + 8 * j;
            if (c < NOUT) {
                float v = acc[j];
                if (EPILOGUE) v = fmaxf(v + b[c], 0.0f);
                out[(long long)node * NOUT + c] = v;
            }
        }
    }
}

// ---------------- final: out = relu(out * norm_in + b3) (in-place, N x 47) ----------------
__global__ __launch_bounds__(256) void final_kernel(float* out, const float* __restrict__ norm_in,
                                                    const float* __restrict__ b3, int N) {
    int i = blockIdx.x * blockDim.x + threadIdx.x;
    int total = N * 47;
    if (i < total) {
        int n = i / 47;
        int f = i - n * 47;
        out[i] = fmaxf(out[i] * norm_in[n] + b3[f], 0.0f);
    }
}

extern "C" void kernel_launch(void* const* d_in, const int* in_sizes, int n_in,
                              void* d_out, int out_size, void* d_ws, size_t ws_size,
                              hipStream_t stream) {
    const float* x  = (const float*)d_in[0];
    const int*   ei = (const int*)d_in[1];
    const float* W1 = (const float*)d_in[2];
    const float* b1 = (const float*)d_in[3];
    const float* W2 = (const float*)d_in[4];
    const float* b2 = (const float*)d_in[5];
    const float* W3 = (const float*)d_in[6];
    const float* b3 = (const float*)d_in[7];
    float* out = (float*)d_out;

    const int N = NN;
    const int E = in_sizes[1] / 2;
    const int* src = ei;
    const int* dst = ei + E;

    float* ws = (float*)d_ws;
    float* norm_out = ws;               // N
    float* norm_in  = ws + N;           // N
    float* bufA = ws + 2 * (size_t)N;   // N x 128
    float* bufB = bufA + (size_t)N * 128;  // N x 128

    // degrees -> norms
    hipMemsetAsync(norm_out, 0, 2 * (size_t)N * sizeof(float), stream);
    degree_kernel<<<(E + 255) / 256, 256, 0, stream>>>(src, dst, norm_out, norm_in, E);
    norm_kernel<<<(N + 255) / 256, 256, 0, stream>>>(norm_out, norm_in, N);

    // ---- layer 1: agg1 = scatter(x,100); h1 = relu(agg1*nin @ W1 + b1) ----
    hipMemsetAsync(bufA, 0, (size_t)N * 100 * sizeof(float), stream);
    {
        int total = E * 100;
        scatter_kernel<100><<<(total + 255) / 256, 256, 0, stream>>>(x, src, dst, norm_out, bufA, E);
    }
    gemm_kernel<100, 128, true><<<(N + 31) / 32, 256, 0, stream>>>(bufA, W1, b1, norm_in, bufB, N);

    // ---- layer 2: agg2 = scatter(h1,128); h2 = relu(agg2*nin @ W2 + b2) ----
    hipMemsetAsync(bufA, 0, (size_t)N * 128 * sizeof(float), stream);
    {
        int total = E * 128;
        scatter_kernel<128><<<(total + 255) / 256, 256, 0, stream>>>(bufB, src, dst, norm_out, bufA, E);
    }
    gemm_kernel<128, 128, true><<<(N + 31) / 32, 256, 0, stream>>>(bufA, W2, b2, norm_in, bufB, N);

    // ---- layer 3 (reordered): y = h2 @ W3 (N x 47); out = relu(scatter(y,47)*nin + b3) ----
    gemm_kernel<128, 47, false><<<(N + 31) / 32, 256, 0, stream>>>(bufB, W3, nullptr, nullptr, bufA, N);
    hipMemsetAsync(out, 0, (size_t)N * 47 * sizeof(float), stream);
    {
        int total = E * 47;
        scatter_kernel<47><<<(total + 255) / 256, 256, 0, stream>>>(bufA, src, dst, norm_out, out, E);
    }
    final_kernel<<<(N * 47 + 255) / 256, 256, 0, stream>>>(out, norm_in, b3, N);
}